// Round 10
// baseline (170.853 us; speedup 1.0000x reference)
//
#include <hip/hip_runtime.h>
#include <hip/hip_bf16.h>

// SizeInvBlock: upsample3x(nearest) -> per-sample dilated 3x3 conv -> maxpool3 -> BN(train) -> relu
// Factorization: conv on the 3x-upsampled image only samples original 32x32 pixels:
//   out[o,y,x] = bias[o] + sum_{ki,kj} T[kikj][o, r_ki(y), c_kj(x)]
//   T[kikj][o,i,j] = sum_c W[o,c,ki,kj] * X[c,i,j]   (one GEMM, 9x fewer FLOPs than direct conv)
// R10: k2 VALU diet:
//   - selector/geometry table precomputed per-sample in k0 (block-uniform work
//     was being redone per-lane: int div + 12 floordiv3 + 12 sels)
//   - outputs paired as (q, q+16) per thread: taps arrive via ds_read2_b32
//     (offsets 0/+16), sums/max in float2 -> v_pk_add/max_f32
// k1 = R5-verbatim (best measured); k3 at its 67 MB traffic floor.
//
// ws layout (bytes):
//   [0,      1024)    stats: sum[128], sumsq[128] (f32, atomic; zeroed by k0_all)
//   [1024,   5120)    seltab int32 [64 b][16]
//   [8192,   155648)  A bf16 [1152][64]   (m = (ki*3+kj)*128 + o, k = cin)
//   [155648, 8544256) XbT bf16 [64 b][1024 n][64 c]
//   [8544256,159539200) T bf16 [1152][65536]  (n = b*1024 + i*32 + j)

typedef __attribute__((ext_vector_type(8))) short bf16x8;
typedef __attribute__((ext_vector_type(4))) float f32x4;
typedef __attribute__((ext_vector_type(2))) float f32x2;
typedef __attribute__((ext_vector_type(8))) unsigned short us8;

#define BN 65536   // T n-dimension (all 64 samples)

__device__ __forceinline__ unsigned short f2bf(float f) {
    unsigned u = __float_as_uint(f);
    u += 0x7fffu + ((u >> 16) & 1u);
    return (unsigned short)(u >> 16);
}
__device__ __forceinline__ float bf2f(unsigned short s) {
    return __uint_as_float(((unsigned)s) << 16);
}
__device__ __forceinline__ int floordiv3(int t) {
    return (t >= 0) ? (t / 3) : -((2 - t) / 3);
}

// ---- K0: merged prep: X transpose->bf16, W pack->bf16, stats zero, seltab
// blocks 0..1023: XbT; 1024..1311: A; 1312: stats + seltab.
__global__ __launch_bounds__(256) void k0_all(const float* __restrict__ x,
                                              const float* __restrict__ w,
                                              const int* __restrict__ hh,
                                              const int* __restrict__ ww,
                                              unsigned short* __restrict__ xbt,
                                              unsigned short* __restrict__ A,
                                              float* __restrict__ stats,
                                              int* __restrict__ seltab) {
    const int bid = blockIdx.x;
    const int tid = threadIdx.x;
    if (bid < 1024) {
        const int n = (bid & 15) * 64 + (tid & 63);
        const int cg = tid >> 6;
        const int b = bid >> 4;
        #pragma unroll
        for (int j2 = 0; j2 < 2; ++j2) {
            int c8 = cg * 2 + j2;                 // 0..7
            us8 r;
            #pragma unroll
            for (int j = 0; j < 8; ++j)
                r[j] = f2bf(x[(((b << 6) + c8 * 8 + j) << 10) + n]);
            *reinterpret_cast<us8*>(xbt + ((size_t)(b << 10) + n) * 64 + c8 * 8) = r;
        }
    } else if (bid < 1312) {
        int gid = (bid - 1024) * 256 + tid;       // < 73728
        int m = gid >> 6, c = gid & 63;
        int kk = m >> 7, o = m & 127;
        A[gid] = f2bf(w[(o * 64 + c) * 9 + kk]);
    } else {
        stats[tid] = 0.f;                          // 256 floats = sum+sumsq
        if (tid < 64) {
            const int b = tid;
            int dh = 96 / hh[b]; if (dh < 1) dh = 1;
            int dw = 96 / ww[b]; if (dw < 1) dw = 1;
            int* st = seltab + b * 16;
            int g0 = floordiv3(-dh), g2 = floordiv3(dh);
            int f0 = floordiv3(-dw), f2 = floordiv3(dw);
            st[0] = g0; st[1] = g2; st[2] = f0; st[3] = f2;
            #pragma unroll
            for (int t = 0; t < 3; ++t) {
                st[4 + t]  = floordiv3(t - dh) - g0;   // r0sel
                st[7 + t]  = floordiv3(t + dh) - g2;   // r2sel
                st[10 + t] = floordiv3(t - dw) - f0;   // c0sel
                st[13 + t] = floordiv3(t + dw) - f2;   // c2sel
            }
        }
    }
}

// ---- K1: GEMM A[1152x64] @ XbT^T[64 x 65536] -> T bf16 (R5 verbatim) -----
// grid (512 nt, 9 mt), 256 thr (2x2 wave grid), tile 128m x 128n, K=64.
__global__ __launch_bounds__(256) void k1_gemm(const unsigned short* __restrict__ XbT,
                                               const unsigned short* __restrict__ A,
                                               unsigned short* __restrict__ T) {
    __shared__ union {
        struct { us8 lA[8 * 129]; us8 lB[8 * 129]; } in;   // 33024 B
        unsigned short ot[128 * 132];                       // 33792 B
    } sm;
    const int tid = threadIdx.x;
    const int nt = blockIdx.x;    // 0..511
    const int mt = blockIdx.y;    // 0..8

    #pragma unroll
    for (int i = 0; i < 4; ++i) {
        int gid = i * 256 + tid;
        int row = gid >> 3, ch = gid & 7; // ch fastest -> coalesced 16B/lane
        sm.in.lA[ch * 129 + row] = *reinterpret_cast<const us8*>(
            A + (size_t)(mt * 128 + row) * 64 + ch * 8);
    }
    #pragma unroll
    for (int i = 0; i < 4; ++i) {
        int gid = i * 256 + tid;
        int row = gid >> 3, ch = gid & 7;
        sm.in.lB[ch * 129 + row] = *reinterpret_cast<const us8*>(
            XbT + ((size_t)nt * 128 + row) * 64 + ch * 8);
    }
    __syncthreads();

    const int wave = tid >> 6, lane = tid & 63;
    const int quad = lane >> 4, l15 = lane & 15;
    const int wm = wave & 1, wn = wave >> 1;
    const bf16x8* pA = reinterpret_cast<const bf16x8*>(sm.in.lA);
    const bf16x8* pB = reinterpret_cast<const bf16x8*>(sm.in.lB);

    f32x4 acc[4][4] = {};
    #pragma unroll
    for (int ks = 0; ks < 2; ++ks) {
        const int kg = ks * 4 + quad;
        bf16x8 aF[4], bF[4];
        #pragma unroll
        for (int mi = 0; mi < 4; ++mi)
            aF[mi] = pA[kg * 129 + wm * 64 + mi * 16 + l15];
        #pragma unroll
        for (int ni = 0; ni < 4; ++ni)
            bF[ni] = pB[kg * 129 + wn * 64 + ni * 16 + l15];
        #pragma unroll
        for (int mi = 0; mi < 4; ++mi)
            #pragma unroll
            for (int ni = 0; ni < 4; ++ni)
                acc[mi][ni] = __builtin_amdgcn_mfma_f32_16x16x32_bf16(aF[mi], bF[ni], acc[mi][ni], 0, 0, 0);
    }
    __syncthreads();   // frags consumed; reuse LDS for output tile

    {
        const int mloc = wm * 64 + quad * 4;
        const int nloc = wn * 64 + l15;
        #pragma unroll
        for (int mi = 0; mi < 4; ++mi)
            #pragma unroll
            for (int r = 0; r < 4; ++r) {
                unsigned short* dst = &sm.ot[(mloc + mi * 16 + r) * 132 + nloc];
                #pragma unroll
                for (int ni = 0; ni < 4; ++ni)
                    dst[ni * 16] = f2bf(acc[mi][ni][r]);
            }
    }
    __syncthreads();

    #pragma unroll
    for (int i = 0; i < 8; ++i) {
        int cid = i * 256 + tid;
        int row = cid >> 4, ch = cid & 15;
        us8 v = *reinterpret_cast<const us8*>(&sm.ot[row * 132 + ch * 8]);
        *reinterpret_cast<us8*>(T + (size_t)(mt * 128 + row) * BN + (size_t)nt * 128 + ch * 8) = v;
    }
}

// ---- K2: LDS-staged 36-tap gather + maxpool3 + bias + BN stats -----------
// grid (o=128, b=64), 512 thr. Thread = (q, p), outputs cols q and q+16 of
// row p, packed float2 (ds_read2_b32 offsets 0/+16; v_pk_add/max). LDS: 9
// planes of 33 rows x 40 f32 (4-col pads both sides, row 32 = zeros).
#define PLS (33 * 40)
__global__ __launch_bounds__(512) void k2_gather(const unsigned short* __restrict__ T,
                                                 const float* __restrict__ bias,
                                                 const int* __restrict__ seltab,
                                                 float* __restrict__ out,
                                                 float* __restrict__ stats) {
    __shared__ float lt[9 * PLS + 4];
    __shared__ float red[16];
    const int tid = threadIdx.x;
    const int o = blockIdx.x, b = blockIdx.y;

    // zero pad columns (rows 0..31, cols {0..3, 36..39})
    #pragma unroll
    for (int it = 0; it < 5; ++it) {
        int i = it * 512 + tid;
        if (i < 9 * 32 * 8) {
            int pr = i >> 3, c = i & 7;
            int kk = pr >> 5, r = pr & 31;
            lt[kk * PLS + r * 40 + (c < 4 ? c : c + 32)] = 0.f;
        }
    }
    // zero row 32 of each plane; slack zeroed separately (in-bounds)
    if (tid < 9 * 40) {
        int kk = tid / 40, c = tid - kk * 40;
        lt[kk * PLS + 32 * 40 + c] = 0.f;
    }
    if (tid < 4) lt[9 * PLS + tid] = 0.f;
    // stage 9 planes (1024 bf16 contiguous each) -> f32 padded rows
    const unsigned short* Tb = T + (size_t)o * BN + (size_t)b * 1024;
    for (int i = tid; i < 9 * 128; i += 512) {
        int kk = i >> 7, c8 = i & 127;
        us8 v = *reinterpret_cast<const us8*>(Tb + (size_t)kk * 128 * BN + c8 * 8);
        int r = c8 >> 2, cb = (c8 & 3) * 8;
        float* dst = &lt[kk * PLS + r * 40 + 4 + cb];
        f32x4 lo, hi;
        lo[0] = bf2f(v[0]); lo[1] = bf2f(v[1]); lo[2] = bf2f(v[2]); lo[3] = bf2f(v[3]);
        hi[0] = bf2f(v[4]); hi[1] = bf2f(v[5]); hi[2] = bf2f(v[6]); hi[3] = bf2f(v[7]);
        *reinterpret_cast<f32x4*>(dst) = lo;
        *reinterpret_cast<f32x4*>(dst + 4) = hi;
    }
    __syncthreads();

    // selector table (block-uniform, precomputed in k0)
    const int* st = seltab + b * 16;
    const int g0 = st[0], g2 = st[1], f0 = st[2], f2 = st[3];
    int r0s[3], r2s[3], c0s[3], c2s[3];
    #pragma unroll
    for (int t = 0; t < 3; ++t) {
        r0s[t] = st[4 + t]; r2s[t] = st[7 + t];
        c0s[t] = st[10 + t]; c2s[t] = st[13 + t];
    }

    const int q = tid & 15, p = tid >> 4;     // outputs (p, q) and (p, q+16)
    const int qoff = q + 4;
    int rA0 = p + g0;     rA0 = ((unsigned)rA0 < 32u) ? rA0 : 32;
    int rB0 = p + g0 + 1; rB0 = ((unsigned)rB0 < 32u) ? rB0 : 32;
    int rA2 = p + g2;     rA2 = ((unsigned)rA2 < 32u) ? rA2 : 32;
    int rB2 = p + g2 + 1; rB2 = ((unsigned)rB2 < 32u) ? rB2 : 32;

    // paired tap load: cols (c, c+16) of one padded row -> ds_read2_b32
    auto ld2 = [&](int plane, int row, int csh) -> f32x2 {
        const float* bp = &lt[plane * PLS + row * 40 + qoff + csh];
        f32x2 r; r.x = bp[0]; r.y = bp[16]; return r;
    };

    f32x2 u0[2][3], u1[3], u2[2][3];
    {   // ki = 0 (planes 0..2), rows rA0/rB0
        f32x2 p0Aa = ld2(0, rA0, f0), p0Ab = ld2(0, rA0, f0 + 1);
        f32x2 p0Ba = ld2(0, rB0, f0), p0Bb = ld2(0, rB0, f0 + 1);
        f32x2 sA = ld2(1, rA0, 0),    sB = ld2(1, rB0, 0);
        f32x2 p2Aa = ld2(2, rA0, f2), p2Ab = ld2(2, rA0, f2 + 1);
        f32x2 p2Ba = ld2(2, rB0, f2), p2Bb = ld2(2, rB0, f2 + 1);
        #pragma unroll
        for (int x3 = 0; x3 < 3; ++x3) {
            u0[0][x3] = (c0s[x3] ? p0Ab : p0Aa) + sA + (c2s[x3] ? p2Ab : p2Aa);
            u0[1][x3] = (c0s[x3] ? p0Bb : p0Ba) + sB + (c2s[x3] ? p2Bb : p2Ba);
        }
    }
    {   // ki = 1 (planes 3..5), row p (never shifted)
        f32x2 m0a = ld2(3, p, f0), m0b = ld2(3, p, f0 + 1);
        f32x2 ms  = ld2(4, p, 0);
        f32x2 m2a = ld2(5, p, f2), m2b = ld2(5, p, f2 + 1);
        #pragma unroll
        for (int x3 = 0; x3 < 3; ++x3)
            u1[x3] = (c0s[x3] ? m0b : m0a) + ms + (c2s[x3] ? m2b : m2a);
    }
    {   // ki = 2 (planes 6..8), rows rA2/rB2
        f32x2 p0Aa = ld2(6, rA2, f0), p0Ab = ld2(6, rA2, f0 + 1);
        f32x2 p0Ba = ld2(6, rB2, f0), p0Bb = ld2(6, rB2, f0 + 1);
        f32x2 sA = ld2(7, rA2, 0),    sB = ld2(7, rB2, 0);
        f32x2 p2Aa = ld2(8, rA2, f2), p2Ab = ld2(8, rA2, f2 + 1);
        f32x2 p2Ba = ld2(8, rB2, f2), p2Bb = ld2(8, rB2, f2 + 1);
        #pragma unroll
        for (int x3 = 0; x3 < 3; ++x3) {
            u2[0][x3] = (c0s[x3] ? p0Ab : p0Aa) + sA + (c2s[x3] ? p2Ab : p2Aa);
            u2[1][x3] = (c0s[x3] ? p0Bb : p0Ba) + sB + (c2s[x3] ? p2Bb : p2Ba);
        }
    }

    f32x2 best = {-3.4e38f, -3.4e38f};
    #pragma unroll
    for (int y3 = 0; y3 < 3; ++y3)
        #pragma unroll
        for (int x3 = 0; x3 < 3; ++x3) {
            f32x2 s = (r0s[y3] ? u0[1][x3] : u0[0][x3])
                    + u1[x3]
                    + (r2s[y3] ? u2[1][x3] : u2[0][x3]);
            best = __builtin_elementwise_max(best, s);
        }
    const float bias_o = bias[o];
    float vx = best.x + bias_o, vy = best.y + bias_o;
    const size_t obase = (((size_t)b * 128 + o) * 32 + p) * 32 + q;
    out[obase] = vx;
    out[obase + 16] = vy;

    // stats: wave reduce -> LDS -> block reduce -> 2 atomics
    float s1 = vx + vy, s2 = vx * vx + vy * vy;
    #pragma unroll
    for (int m = 32; m >= 1; m >>= 1) {
        s1 += __shfl_xor(s1, m, 64);
        s2 += __shfl_xor(s2, m, 64);
    }
    if ((tid & 63) == 0) {
        red[tid >> 6] = s1;
        red[8 + (tid >> 6)] = s2;
    }
    __syncthreads();
    if (tid < 64) {
        float a1 = (tid < 8) ? red[tid] : 0.f;
        float a2 = (tid < 8) ? red[8 + tid] : 0.f;
        #pragma unroll
        for (int m = 4; m >= 1; m >>= 1) {
            a1 += __shfl_xor(a1, m, 64);
            a2 += __shfl_xor(a2, m, 64);
        }
        if (tid == 0) {
            atomicAdd(&stats[o], a1);
            atomicAdd(&stats[128 + o], a2);
        }
    }
}

// ---- K3: BN finalize + affine + relu, in-place on d_out ------------------
__global__ __launch_bounds__(256) void k3_bn(float4* __restrict__ out,
                                             const float* __restrict__ stats,
                                             const float* __restrict__ gamma,
                                             const float* __restrict__ beta) {
    int i4 = blockIdx.x * 256 + threadIdx.x;   // 0..2097151
    int o = (i4 >> 8) & 127;
    const float invN = 1.0f / 65536.0f;
    float mean = stats[o] * invN;
    float var = stats[128 + o] * invN - mean * mean;
    float inv = rsqrtf(var + 1e-5f);
    float sc = gamma[o] * inv;
    float sh = beta[o] - mean * sc;
    float4 v = out[i4];
    v.x = fmaxf(fmaf(v.x, sc, sh), 0.f);
    v.y = fmaxf(fmaf(v.y, sc, sh), 0.f);
    v.z = fmaxf(fmaf(v.z, sc, sh), 0.f);
    v.w = fmaxf(fmaf(v.w, sc, sh), 0.f);
    out[i4] = v;
}

extern "C" void kernel_launch(void* const* d_in, const int* in_sizes, int n_in,
                              void* d_out, int out_size, void* d_ws, size_t ws_size,
                              hipStream_t stream) {
    const float* x     = (const float*)d_in[0];
    const int*   h     = (const int*)d_in[1];
    const int*   w     = (const int*)d_in[2];
    const float* wt    = (const float*)d_in[3];
    const float* bias  = (const float*)d_in[4];
    const float* gamma = (const float*)d_in[5];
    const float* beta  = (const float*)d_in[6];
    float* out = (float*)d_out;
    char* ws = (char*)d_ws;

    float*          stats  = (float*)(ws + 0);
    int*            seltab = (int*)(ws + 1024);
    unsigned short* A      = (unsigned short*)(ws + 8192);
    unsigned short* XbT    = (unsigned short*)(ws + 155648);
    unsigned short* T      = (unsigned short*)(ws + 8544256);

    k0_all<<<1313, 256, 0, stream>>>(x, wt, h, w, XbT, A, stats, seltab);
    k1_gemm<<<dim3(512, 9), 256, 0, stream>>>(XbT, A, T);
    k2_gather<<<dim3(128, 64), 512, 0, stream>>>(T, bias, seltab, out, stats);
    k3_bn<<<8192, 256, 0, stream>>>((float4*)out, stats, gamma, beta);
}